// Round 2
// baseline (110.644 us; speedup 1.0000x reference)
//
#include <hip/hip_runtime.h>
#include <hip/hip_bf16.h>

// MultiHeadLiftLayer:
//   y0 = x0 @ W[:128]  (per-node, 50000x8)
//   y1 = x0 @ W[128:]  (per-node, 50000x8)
//   edge_signal[e,h] = relu(y0[src[e],h] + y1[tgt[e],h])
//   out = cat([edge_signal, x_1], axis=1)   // (625000, 72) f32
//
// Kernel 1: per-node projection into d_ws (50000 x 16 floats, 3.2 MB).
// Kernel 2: two-phase tiled edge kernel:
//   phase 1: 1 edge/thread, gather y, compute heads -> LDS
//   phase 2: pure streaming store of the block's contiguous output tile
//            (LDS for head slots, x1 for the rest). No global gathers in
//            the hot loop -> store stream runs at memcpy rate.

#define NUM_NODES 50000
#define C0 128
#define HEADS 8
#define NODES_PER_BLK 16
#define XS_STRIDE 132   // 128 + 4 pad
#define EPB 256         // edges per block (edge kernel)

__global__ __launch_bounds__(256) void node_proj_kernel(
    const float* __restrict__ x0, const float* __restrict__ W,
    float* __restrict__ y, int num_nodes)
{
    __shared__ float Ws[2 * C0 * HEADS];          // 8 KB
    __shared__ float xs[NODES_PER_BLK * XS_STRIDE];

    for (int i = threadIdx.x; i < 2 * C0 * HEADS; i += 256) Ws[i] = W[i];

    const int nodeBase = blockIdx.x * NODES_PER_BLK;
    for (int i = threadIdx.x; i < NODES_PER_BLK * C0; i += 256) {
        int r = i >> 7;
        int c = i & (C0 - 1);
        int n = nodeBase + r;
        xs[r * XS_STRIDE + c] = (n < num_nodes) ? x0[n * C0 + c] : 0.f;
    }
    __syncthreads();

    const int local = threadIdx.x >> 4;
    const int slot  = threadIdx.x & 15;   // half*8 + h
    const int half  = slot >> 3;
    const int h     = slot & 7;

    const float* xr = &xs[local * XS_STRIDE];
    const float* Wr = &Ws[half * C0 * HEADS + h];

    float acc = 0.f;
    #pragma unroll 8
    for (int c = 0; c < C0; ++c)
        acc = fmaf(xr[c], Wr[c * HEADS], acc);

    const int n = nodeBase + local;
    if (n < num_nodes) y[n * 16 + slot] = acc;
}

__global__ __launch_bounds__(256) void edge_out_kernel(
    const float* __restrict__ y, const float* __restrict__ x1,
    const int* __restrict__ adj, float* __restrict__ out, int E)
{
    const float4* __restrict__ yv  = (const float4*)y;   // 4 float4 per node
    const float4* __restrict__ x1v = (const float4*)x1;  // 16 float4 per edge
    float4* __restrict__ outv = (float4*)out;            // 18 float4 per edge

    __shared__ float4 head[EPB][2];                      // 8 KB

    const int be  = blockIdx.x * EPB;
    const int tid = threadIdx.x;

    // Phase 1: one edge per thread — gather + compute heads into LDS.
    const int e = be + tid;
    if (e < E) {
        const int s = adj[e];
        const int t = adj[E + e];
        const float4 a0 = yv[s * 4 + 0];
        const float4 a1 = yv[s * 4 + 1];
        const float4 b0 = yv[t * 4 + 2];
        const float4 b1 = yv[t * 4 + 3];
        float4 h0, h1;
        h0.x = fmaxf(a0.x + b0.x, 0.f);
        h0.y = fmaxf(a0.y + b0.y, 0.f);
        h0.z = fmaxf(a0.z + b0.z, 0.f);
        h0.w = fmaxf(a0.w + b0.w, 0.f);
        h1.x = fmaxf(a1.x + b1.x, 0.f);
        h1.y = fmaxf(a1.y + b1.y, 0.f);
        h1.z = fmaxf(a1.z + b1.z, 0.f);
        h1.w = fmaxf(a1.w + b1.w, 0.f);
        head[tid][0] = h0;
        head[tid][1] = h1;
    }
    __syncthreads();

    // Phase 2: pure streaming store of this block's contiguous out tile.
    const int n   = (E - be < EPB) ? (E - be) : EPB;
    const int n4  = n * 18;
    const float4* __restrict__ x1b  = x1v  + (size_t)be * 16;
    float4* __restrict__       outb = outv + (size_t)be * 18;

    for (int i = tid; i < n4; i += 256) {
        const int el = i / 18;             // magic-mul
        const int j  = i - el * 18;
        const float4 v = (j >= 2) ? x1b[el * 16 + (j - 2)] : head[el][j];
        outb[i] = v;
    }
}

extern "C" void kernel_launch(void* const* d_in, const int* in_sizes, int n_in,
                              void* d_out, int out_size, void* d_ws, size_t ws_size,
                              hipStream_t stream) {
    const float* x0  = (const float*)d_in[0];
    const int*   adj = (const int*)d_in[1];   // JAX demotes int64->int32
    const float* x1  = (const float*)d_in[2];
    const float* W   = (const float*)d_in[3];
    float* out = (float*)d_out;
    float* y   = (float*)d_ws;                // 50000*16 floats = 3.2 MB

    const int E = in_sizes[1] / 2;            // 625000

    {
        dim3 grid((NUM_NODES + NODES_PER_BLK - 1) / NODES_PER_BLK);
        node_proj_kernel<<<grid, 256, 0, stream>>>(x0, W, y, NUM_NODES);
    }
    {
        dim3 grid((E + EPB - 1) / EPB);       // 2442 blocks
        edge_out_kernel<<<grid, 256, 0, stream>>>(y, x1, adj, out, E);
    }
}